// Round 6
// baseline (174.174 us; speedup 1.0000x reference)
//
#include <hip/hip_runtime.h>
#include <math.h>

#define T_LEN 256
#define HID 10

typedef float v2f __attribute__((ext_vector_type(2)));

__device__ __forceinline__ v2f mk2(float a, float b) { v2f r; r.x = a; r.y = b; return r; }
__device__ __forceinline__ v2f splat2(float a) { return mk2(a, a); }

// setup-only accurate softplus
__device__ __forceinline__ float softplus_f(float x) {
    return fmaxf(x, 0.0f) + log1pf(expf(-fabsf(x)));
}
__device__ __forceinline__ float samp(const float* mu, const float* rho,
                                      const float* eps, int i) {
    return mu[i] + softplus_f(rho[i]) * eps[i];
}

#define NLOG2E (-1.442695040888963f)   // i,f,o columns pre-scale
#define P2LOG2E (2.885390081777927f)   // g column pre-scale

// activations on PRE-SCALED gate inputs (scale folded into weights):
__device__ __forceinline__ float sig_pre(float a) {
    return __builtin_amdgcn_rcpf(1.0f + __builtin_amdgcn_exp2f(a));
}
__device__ __forceinline__ float tanh_pre(float a) {
    return fmaf(-2.0f, __builtin_amdgcn_rcpf(__builtin_amdgcn_exp2f(a) + 1.0f), 1.0f);
}
// runtime tanh for c (not pre-scalable)
__device__ __forceinline__ float fast_tanh(float x) {
    float e = __builtin_amdgcn_exp2f(P2LOG2E * x);
    return fmaf(-2.0f, __builtin_amdgcn_rcpf(e + 1.0f), 1.0f);
}

// DPP row rotate-right by R within each 16-lane row (VALU pipe, no DS):
// dst lane i = src lane (i - R) mod 16.  (convention verified correct in R4)
#define ROTF(hi, R) __int_as_float(__builtin_amdgcn_mov_dpp((hi), 0x120 + (R), 0xF, 0xF, true))

struct Wreg {
    // wsel01[r] = whh row ((k - r) & 15), col pair {i,f} of this lane's unit k,
    // PRE-SCALED (zero for pad rows >= HID and pad lanes k >= HID)
    v2f wsel01[16], wsel23[16];
    v2f wih01, wih23, b01, b23;   // pre-scaled
};

// One LSTM step for one element. h distributed one unit per lane across the
// 16-lane row (lanes 10..15 stay 0 via zero weights). 15 independent DPP
// rotations of hk feed two accumulator chains per gate pair.
__device__ __forceinline__ float lstm_step(const Wreg& w, float xt, float hk,
                                           float& c)
{
    const int hi = __float_as_int(hk);
    v2f x2 = splat2(xt);
    v2f e01 = __builtin_elementwise_fma(x2, w.wih01, w.b01);
    v2f e23 = __builtin_elementwise_fma(x2, w.wih23, w.b23);
    v2f o01 = w.wsel01[0] * splat2(hk);
    v2f o23 = w.wsel23[0] * splat2(hk);
#define RSTEP(R, A01, A23)                                            \
    {                                                                 \
        v2f hr = splat2(ROTF(hi, R));                                 \
        A01 = __builtin_elementwise_fma(hr, w.wsel01[R], A01);        \
        A23 = __builtin_elementwise_fma(hr, w.wsel23[R], A23);        \
    }
    RSTEP(1,  e01, e23)
    RSTEP(2,  o01, o23)
    RSTEP(3,  e01, e23)
    RSTEP(4,  o01, o23)
    RSTEP(5,  e01, e23)
    RSTEP(6,  o01, o23)
    RSTEP(7,  e01, e23)
    RSTEP(8,  o01, o23)
    RSTEP(9,  e01, e23)
    RSTEP(10, o01, o23)
    RSTEP(11, e01, e23)
    RSTEP(12, o01, o23)
    RSTEP(13, e01, e23)
    RSTEP(14, o01, o23)
    RSTEP(15, e01, e23)
#undef RSTEP
    v2f a01 = e01 + o01;
    v2f a23 = e23 + o23;
    float ig = sig_pre(a01.x);
    float fg = sig_pre(a01.y);
    float gg = tanh_pre(a23.x);
    float og = sig_pre(a23.y);
    c = fmaf(fg, c, ig * gg);
    return og * fast_tanh(c);
}

// One wave per block; TWO elements per 16-lane row (A on hkA, B on hkB; the
// expensive weight registers are shared) -> 8 elements/wave, 8192/8 = 1024
// single-wave blocks = exactly 1 wave per SIMD. No DS ops in the recurrence,
// no SIMD issue-sharing; the two independent element streams interleave to
// hide each other's FMA/transcendental latency.
__global__ __launch_bounds__(64) void bayes_lstm_kernel(
    const float* __restrict__ x,
    const float* __restrict__ w_ih_mu, const float* __restrict__ w_ih_rho,
    const float* __restrict__ w_hh_mu, const float* __restrict__ w_hh_rho,
    const float* __restrict__ b_mu,    const float* __restrict__ b_rho,
    const float* __restrict__ eps_ih,  const float* __restrict__ eps_hh,
    const float* __restrict__ eps_b,
    const float* __restrict__ lin_w,   const float* __restrict__ lin_b,
    float* __restrict__ out, int n_elem)
{
    const int lane = threadIdx.x & 63;
    const int k    = lane & 15;          // unit index within row (pads: 10..15)
    const int row  = lane >> 4;          // 0..3: row within wave
    const int bA   = blockIdx.x * 8 + row * 2;
    const int bB   = bA + 1;
    const int bAe  = (bA < n_elem) ? bA : (n_elem - 1);
    const int bBe  = (bB < n_elem) ? bB : (n_elem - 1);
    const bool un  = (k < HID);

    // ---- sample weights into registers, pre-permuted + PRE-SCALED ----
    Wreg w;
    w.wih01 = splat2(0.f); w.wih23 = splat2(0.f);
    w.b01 = splat2(0.f);   w.b23 = splat2(0.f);
    const v2f s01 = mk2(NLOG2E, NLOG2E);      // {i, f}
    const v2f s23 = mk2(P2LOG2E, NLOG2E);     // {g, o}
    if (un) {
        const int c0 = k, c1 = HID + k, c2 = 2 * HID + k, c3 = 3 * HID + k;
        w.wih01 = s01 * mk2(samp(w_ih_mu, w_ih_rho, eps_ih, c0), samp(w_ih_mu, w_ih_rho, eps_ih, c1));
        w.wih23 = s23 * mk2(samp(w_ih_mu, w_ih_rho, eps_ih, c2), samp(w_ih_mu, w_ih_rho, eps_ih, c3));
        w.b01   = s01 * mk2(samp(b_mu, b_rho, eps_b, c0), samp(b_mu, b_rho, eps_b, c1));
        w.b23   = s23 * mk2(samp(b_mu, b_rho, eps_b, c2), samp(b_mu, b_rho, eps_b, c3));
    }
#pragma unroll
    for (int r = 0; r < 16; ++r) {
        const int idx = (k - r) & 15;    // source h index delivered by ROTF(r)
        if (un && idx < HID) {
            const int base = idx * 4 * HID;
            w.wsel01[r] = s01 * mk2(samp(w_hh_mu, w_hh_rho, eps_hh, base + k),
                                    samp(w_hh_mu, w_hh_rho, eps_hh, base + HID + k));
            w.wsel23[r] = s23 * mk2(samp(w_hh_mu, w_hh_rho, eps_hh, base + 2 * HID + k),
                                    samp(w_hh_mu, w_hh_rho, eps_hh, base + 3 * HID + k));
        } else {
            w.wsel01[r] = splat2(0.f);
            w.wsel23[r] = splat2(0.f);
        }
    }

    // ---- recurrence: 64 chunks x 4 steps, x prefetched one chunk ahead ----
    float cA = 0.f, hkA = 0.f, cB = 0.f, hkB = 0.f;
    const float4* xvA = (const float4*)(x + (size_t)bAe * T_LEN);
    const float4* xvB = (const float4*)(x + (size_t)bBe * T_LEN);
    float4 xqA = xvA[0], xqB = xvB[0];
    for (int ch = 0; ch < 64; ++ch) {
        const int nx = (ch < 63) ? ch + 1 : 63;
        float4 xnA = xvA[nx];
        float4 xnB = xvB[nx];
        hkA = lstm_step(w, xqA.x, hkA, cA);
        hkB = lstm_step(w, xqB.x, hkB, cB);
        hkA = lstm_step(w, xqA.y, hkA, cA);
        hkB = lstm_step(w, xqB.y, hkB, cB);
        hkA = lstm_step(w, xqA.z, hkA, cA);
        hkB = lstm_step(w, xqB.z, hkB, cB);
        hkA = lstm_step(w, xqA.w, hkA, cA);
        hkB = lstm_step(w, xqB.w, hkB, cB);
        xqA = xnA; xqB = xnB;
    }

    // ---- linear head: reduce h[k]*lw over the 16-lane row (once, off-loop) ----
    const float lw = un ? lin_w[k] : 0.f;
    float pa = hkA * lw;                 // pad lanes contribute 0
    float pb = hkB * lw;
    pa += __shfl_xor(pa, 1, 16);  pb += __shfl_xor(pb, 1, 16);
    pa += __shfl_xor(pa, 2, 16);  pb += __shfl_xor(pb, 2, 16);
    pa += __shfl_xor(pa, 4, 16);  pb += __shfl_xor(pb, 4, 16);
    pa += __shfl_xor(pa, 8, 16);  pb += __shfl_xor(pb, 8, 16);
    if (k == 0) {
        float b0 = lin_b[0];
        if (bA < n_elem) out[bA] = pa + b0;
        if (bB < n_elem) out[bB] = pb + b0;
    }
}

extern "C" void kernel_launch(void* const* d_in, const int* in_sizes, int n_in,
                              void* d_out, int out_size, void* d_ws, size_t ws_size,
                              hipStream_t stream) {
    const float* x        = (const float*)d_in[0];
    const float* w_ih_mu  = (const float*)d_in[1];
    const float* w_ih_rho = (const float*)d_in[2];
    const float* w_hh_mu  = (const float*)d_in[3];
    const float* w_hh_rho = (const float*)d_in[4];
    const float* b_mu     = (const float*)d_in[5];
    const float* b_rho    = (const float*)d_in[6];
    const float* eps_ih   = (const float*)d_in[7];
    const float* eps_hh   = (const float*)d_in[8];
    const float* eps_b    = (const float*)d_in[9];
    const float* lin_w    = (const float*)d_in[10];
    const float* lin_b    = (const float*)d_in[11];
    float* out = (float*)d_out;

    const int n_b = in_sizes[0] / T_LEN;     // 8192
    dim3 grid((n_b + 7) / 8), block(64);     // 1 wave/block, 8 elements/wave
    hipLaunchKernelGGL(bayes_lstm_kernel, grid, block, 0, stream,
                       x, w_ih_mu, w_ih_rho, w_hh_mu, w_hh_rho, b_mu, b_rho,
                       eps_ih, eps_hh, eps_b, lin_w, lin_b, out, n_b);
}